// Round 1
// baseline (1874.736 us; speedup 1.0000x reference)
//
#include <hip/hip_runtime.h>
#include <math.h>

// Problem constants (fixed by reference)
#define NB   64
#define NT   512
#define DH   1024
#define HID_OFF  33554432   // 64*512*1024
#define HC_SZ    65536      // 64*1024

// ws layout (floats):
//  [0]      A_T_ih [16][1024]
//  [16384]  A_T_hh [16][1024]
//  [32768]  M2ih   [16][256]
//  [36864]  M2hh   [16][256]
//  [40960]  y_ih   [32768][256]   (32 MB)

__device__ __forceinline__ float sigm(float x) { return 1.f / (1.f + __expf(-x)); }
__device__ __forceinline__ float tanh_fast(float x) {
    float e = __expf(2.f * x);
    return 1.f - 2.f / (e + 1.f);
}

// ---------------- K0: build A_T = (g1*g2*g3)^T and M2 = g5*g6 ----------------
__global__ __launch_bounds__(256) void k0_build(
    const float* __restrict__ g1, const float* __restrict__ g2,
    const float* __restrict__ g3, const float* __restrict__ g5,
    const float* __restrict__ g6, float* __restrict__ A_T, float* __restrict__ M2)
{
    __shared__ float M1[1024];  // [i1][j][c] = i1*128 + j*16 + c
    int tid = threadIdx.x;
    for (int idx = tid; idx < 1024; idx += 256) {
        int i1 = idx >> 7, j = (idx >> 4) & 7, c = idx & 15;
        float s = 0.f;
        for (int a = 0; a < 16; ++a) s += g1[i1 * 16 + a] * g2[a * 128 + j * 16 + c];
        M1[idx] = s;
    }
    __syncthreads();
    // A_T[d*1024 + i],  i = i1*128 + j*16 + k
    for (int idx = tid; idx < 16384; idx += 256) {
        int d = idx >> 10, i = idx & 1023;
        int i1 = i >> 7, j = (i >> 4) & 7, k = i & 15;
        float s = 0.f;
        for (int c = 0; c < 16; ++c) s += M1[i1 * 128 + j * 16 + c] * g3[c * 256 + k * 16 + d];
        A_T[idx] = s;
    }
    // M2[e*256 + m*16 + p]
    for (int idx = tid; idx < 4096; idx += 256) {
        int e = idx >> 8, mp = idx & 255;
        int m = mp >> 4, p = mp & 15;
        float s = 0.f;
        for (int f = 0; f < 16; ++f) s += g5[e * 256 + m * 16 + f] * g6[f * 16 + p];
        M2[idx] = s;
    }
}

// ---------------- K1: y_ih[row][256] = (x[row]·A_ih)·g4ih, rows = b*T + t ----
__global__ __launch_bounds__(256) void k1_zy(
    const float* __restrict__ x, const float* __restrict__ A_T,
    const float* __restrict__ g4, float* __restrict__ y_out)
{
    __shared__ float P[16 * 257];           // partials [d][tid], padded stride
    __shared__ float Q[256];                // [d][s]
    __shared__ __align__(16) float Zf[16];
    int tid = threadIdx.x;

    float a_reg[4][16];                     // A[tid+256k][d]
    #pragma unroll
    for (int k = 0; k < 4; ++k)
        #pragma unroll
        for (int d = 0; d < 16; ++d)
            a_reg[k][d] = A_T[d * 1024 + tid + 256 * k];

    float g4r[16];                          // g4[d][tid] (tid = n*16+e)
    #pragma unroll
    for (int d = 0; d < 16; ++d) g4r[d] = g4[d * 256 + tid];

    int row0 = blockIdx.x * 16;
    for (int r = 0; r < 16; ++r) {
        int row = row0 + r;
        float xv[4];
        #pragma unroll
        for (int k = 0; k < 4; ++k) xv[k] = x[(size_t)row * 1024 + tid + 256 * k];
        #pragma unroll
        for (int d = 0; d < 16; ++d) {
            float acc = 0.f;
            #pragma unroll
            for (int k = 0; k < 4; ++k) acc += xv[k] * a_reg[k][d];
            P[d * 257 + tid] = acc;
        }
        __syncthreads();
        {
            int d = tid & 15, s = tid >> 4;
            float v = 0.f;
            #pragma unroll
            for (int j2 = 0; j2 < 16; ++j2) v += P[d * 257 + s * 16 + j2];
            Q[d * 16 + s] = v;
        }
        __syncthreads();
        if (tid < 16) {
            float v = 0.f;
            #pragma unroll
            for (int s2 = 0; s2 < 16; ++s2) v += Q[tid * 16 + s2];
            Zf[tid] = v;
        }
        __syncthreads();
        {
            float y = 0.f;
            #pragma unroll
            for (int d = 0; d < 16; ++d) y += Zf[d] * g4r[d];
            y_out[(size_t)row * 256 + tid] = y;
        }
        __syncthreads();
    }
}

// ---------------- K2: sequential LSTM, one block per batch row --------------
__global__ __launch_bounds__(1024) void k2_lstm(
    const float* __restrict__ A_T_hh, const float* __restrict__ g4hh,
    const float* __restrict__ M2ih, const float* __restrict__ M2hh,
    const float* __restrict__ y_ih_g,
    const float* __restrict__ b_ih, const float* __restrict__ b_hh,
    float* __restrict__ out)
{
    __shared__ __align__(16) float Lh[1024];
    __shared__ __align__(16) float Lz[16];
    __shared__ __align__(16) float Lyi[256];
    __shared__ __align__(16) float Lyh[256];
    __shared__ float Lg4[256 * 17];         // transposed g4hh, stride-17 (bank-safe)

    int tid  = threadIdx.x;
    int b    = blockIdx.x;
    int lane = tid & 63, w = tid >> 6;

    // z-phase A registers: wave w owns d=w; lane l covers i = l + 64k
    float ar[16];
    #pragma unroll
    for (int k = 0; k < 16; ++k) ar[k] = A_T_hh[w * 1024 + lane + 64 * k];

    // stage-2 weights: thread tid -> (n0 = tid>>8, mp = tid&255); gate g uses n = n0+4g
    int mp = tid & 255;
    int n0 = tid >> 8;
    float m2i[16], m2h[16];
    #pragma unroll
    for (int e = 0; e < 16; ++e) {
        m2i[e] = M2ih[e * 256 + mp];
        m2h[e] = M2hh[e * 256 + mp];
    }
    float bias[4];
    #pragma unroll
    for (int g = 0; g < 4; ++g) bias[g] = b_ih[g * 1024 + tid] + b_hh[g * 1024 + tid];

    if (tid < 256) {
        #pragma unroll
        for (int d = 0; d < 16; ++d) Lg4[tid * 17 + d] = g4hh[d * 256 + tid];
    }
    Lh[tid] = 0.f;
    float c = 0.f, h = 0.f;
    __syncthreads();

    const float* yrow = y_ih_g + (size_t)b * NT * 256;
    float*       orow = out + (size_t)b * NT * 1024;

    for (int t = 0; t < NT; ++t) {
        // issue y_ih load early (global, coalesced 1KB)
        float yld = 0.f;
        if (tid < 256) yld = yrow[t * 256 + tid];

        // --- z = h · A_hh (wave w computes z[w]) ---
        float zacc = 0.f;
        #pragma unroll
        for (int k = 0; k < 16; ++k) zacc += Lh[lane + 64 * k] * ar[k];
        #pragma unroll
        for (int m = 32; m >= 1; m >>= 1) zacc += __shfl_xor(zacc, m, 64);
        if (lane == 0) Lz[w] = zacc;
        if (tid < 256) Lyi[tid] = yld;
        __syncthreads();

        // --- y_hh[n,e] = z · g4hh (threads 0..255) ---
        if (tid < 256) {
            float yv = 0.f;
            #pragma unroll
            for (int d = 0; d < 16; ++d) yv += Lz[d] * Lg4[tid * 17 + d];
            Lyh[tid] = yv;
        }
        __syncthreads();

        // --- stage 2: gates[g] = bias + sum_e (y_ih[n0+4g,e]*m2i[e] + y_hh[n0+4g,e]*m2h[e]) ---
        float acc0 = bias[0], acc1 = bias[1], acc2 = bias[2], acc3 = bias[3];
        #pragma unroll
        for (int eb = 0; eb < 4; ++eb) {
            const float4 yi0 = *(const float4*)&Lyi[(n0     ) * 16 + 4 * eb];
            const float4 yh0 = *(const float4*)&Lyh[(n0     ) * 16 + 4 * eb];
            const float4 yi1 = *(const float4*)&Lyi[(n0 +  4) * 16 + 4 * eb];
            const float4 yh1 = *(const float4*)&Lyh[(n0 +  4) * 16 + 4 * eb];
            const float4 yi2 = *(const float4*)&Lyi[(n0 +  8) * 16 + 4 * eb];
            const float4 yh2 = *(const float4*)&Lyh[(n0 +  8) * 16 + 4 * eb];
            const float4 yi3 = *(const float4*)&Lyi[(n0 + 12) * 16 + 4 * eb];
            const float4 yh3 = *(const float4*)&Lyh[(n0 + 12) * 16 + 4 * eb];
            float w0 = m2i[4 * eb + 0], w1 = m2i[4 * eb + 1], w2 = m2i[4 * eb + 2], w3 = m2i[4 * eb + 3];
            float v0 = m2h[4 * eb + 0], v1 = m2h[4 * eb + 1], v2 = m2h[4 * eb + 2], v3 = m2h[4 * eb + 3];
            acc0 += yi0.x * w0 + yi0.y * w1 + yi0.z * w2 + yi0.w * w3
                  + yh0.x * v0 + yh0.y * v1 + yh0.z * v2 + yh0.w * v3;
            acc1 += yi1.x * w0 + yi1.y * w1 + yi1.z * w2 + yi1.w * w3
                  + yh1.x * v0 + yh1.y * v1 + yh1.z * v2 + yh1.w * v3;
            acc2 += yi2.x * w0 + yi2.y * w1 + yi2.z * w2 + yi2.w * w3
                  + yh2.x * v0 + yh2.y * v1 + yh2.z * v2 + yh2.w * v3;
            acc3 += yi3.x * w0 + yi3.y * w1 + yi3.z * w2 + yi3.w * w3
                  + yh3.x * v0 + yh3.y * v1 + yh3.z * v2 + yh3.w * v3;
        }

        // --- elementwise LSTM cell (i,f,g,o = acc0..acc3) ---
        float ig = sigm(acc0);
        float fg = sigm(acc1);
        float gg = tanh_fast(acc2);
        float og = sigm(acc3);
        c = fg * c + ig * gg;
        h = og * tanh_fast(c);

        Lh[tid] = h;                 // safe: all Lh reads of this step done before B1
        orow[t * 1024 + tid] = h;
        __syncthreads();
    }

    // final (h, c)
    out[HID_OFF + b * 1024 + tid] = h;
    out[HID_OFF + HC_SZ + b * 1024 + tid] = c;
}

extern "C" void kernel_launch(void* const* d_in, const int* in_sizes, int n_in,
                              void* d_out, int out_size, void* d_ws, size_t ws_size,
                              hipStream_t stream) {
    const float* x     = (const float*)d_in[0];
    const float* ihg1  = (const float*)d_in[1];
    const float* ihg2  = (const float*)d_in[2];
    const float* ihg3  = (const float*)d_in[3];
    const float* ihg4  = (const float*)d_in[4];
    const float* ihg5  = (const float*)d_in[5];
    const float* ihg6  = (const float*)d_in[6];
    const float* hhg1  = (const float*)d_in[7];
    const float* hhg2  = (const float*)d_in[8];
    const float* hhg3  = (const float*)d_in[9];
    const float* hhg4  = (const float*)d_in[10];
    const float* hhg5  = (const float*)d_in[11];
    const float* hhg6  = (const float*)d_in[12];
    const float* b_ih  = (const float*)d_in[13];
    const float* b_hh  = (const float*)d_in[14];
    float* out = (float*)d_out;

    float* ws    = (float*)d_ws;
    float* ATih  = ws;
    float* AThh  = ws + 16384;
    float* M2ih  = ws + 32768;
    float* M2hh  = ws + 36864;
    float* yih   = ws + 40960;

    hipLaunchKernelGGL(k0_build, dim3(1), dim3(256), 0, stream,
                       ihg1, ihg2, ihg3, ihg5, ihg6, ATih, M2ih);
    hipLaunchKernelGGL(k0_build, dim3(1), dim3(256), 0, stream,
                       hhg1, hhg2, hhg3, hhg5, hhg6, AThh, M2hh);
    hipLaunchKernelGGL(k1_zy, dim3(2048), dim3(256), 0, stream,
                       x, ATih, ihg4, yih);
    hipLaunchKernelGGL(k2_lstm, dim3(NB), dim3(1024), 0, stream,
                       AThh, hhg4, M2ih, M2hh, yih, b_ih, b_hh, out);
}

// Round 2
// 1683.954 us; speedup vs baseline: 1.1133x; 1.1133x over previous
//
#include <hip/hip_runtime.h>
#include <math.h>

// Problem constants (fixed by reference)
#define NB   64
#define NT   512
#define DH   1024
#define HID_OFF  33554432   // 64*512*1024
#define HC_SZ    65536      // 64*1024

// ws layout (floats):
//  [0]       A_T_ih [16][1024]
//  [16384]   A_T_hh [16][1024]
//  [32768]   M2ih   [16][256]
//  [36864]   M2hh   [16][256]
//  [40960]   Whh2   [4096][16]   (g4hh x M2hh folded, u-major)
//  [106496]  pfdump [256]        (prefetch dump, never read)
//  [106752]  y_ih   [32768][256] (32 MB)

typedef float v2f __attribute__((ext_vector_type(2)));

__device__ __forceinline__ v2f mkv2(float a, float b) { v2f r; r.x = a; r.y = b; return r; }

__device__ __forceinline__ void bar_lgkm() {
    // barrier that waits only for LDS/SMEM ops (NOT vmcnt) — keeps HBM
    // stores/prefetches out of the per-step critical path.
    asm volatile("s_waitcnt lgkmcnt(0)\n\ts_barrier" ::: "memory");
}

__device__ __forceinline__ float sigm(float x) { return 1.f / (1.f + __expf(-x)); }
__device__ __forceinline__ float tanh_fast(float x) {
    float e = __expf(2.f * x);
    return 1.f - 2.f / (e + 1.f);
}

// ---------------- K0a: build A_T = (g1*g2*g3)^T and M2 = g5*g6 (both param sets)
__global__ __launch_bounds__(256) void k0_build(
    const float* __restrict__ g1a, const float* __restrict__ g2a,
    const float* __restrict__ g3a, const float* __restrict__ g5a,
    const float* __restrict__ g6a,
    const float* __restrict__ g1b, const float* __restrict__ g2b,
    const float* __restrict__ g3b, const float* __restrict__ g5b,
    const float* __restrict__ g6b,
    float* __restrict__ ATa, float* __restrict__ M2a,
    float* __restrict__ ATb, float* __restrict__ M2b)
{
    const float* g1 = blockIdx.x ? g1b : g1a;
    const float* g2 = blockIdx.x ? g2b : g2a;
    const float* g3 = blockIdx.x ? g3b : g3a;
    const float* g5 = blockIdx.x ? g5b : g5a;
    const float* g6 = blockIdx.x ? g6b : g6a;
    float* A_T = blockIdx.x ? ATb : ATa;
    float* M2  = blockIdx.x ? M2b : M2a;

    __shared__ float Lg1[128], Lg2[2048], Lg3[4096], Lg5[4096], Lg6[256], M1[1024];
    int tid = threadIdx.x;
    for (int i = tid; i < 128;  i += 256) Lg1[i] = g1[i];
    for (int i = tid; i < 2048; i += 256) Lg2[i] = g2[i];
    for (int i = tid; i < 4096; i += 256) Lg3[i] = g3[i];
    for (int i = tid; i < 4096; i += 256) Lg5[i] = g5[i];
    for (int i = tid; i < 256;  i += 256) Lg6[i] = g6[i];
    __syncthreads();
    for (int idx = tid; idx < 1024; idx += 256) {
        int i1 = idx >> 7, j = (idx >> 4) & 7, c = idx & 15;
        float s = 0.f;
        for (int a = 0; a < 16; ++a) s += Lg1[i1 * 16 + a] * Lg2[a * 128 + j * 16 + c];
        M1[idx] = s;
    }
    __syncthreads();
    for (int idx = tid; idx < 16384; idx += 256) {
        int d = idx >> 10, i = idx & 1023;
        int i1 = i >> 7, j = (i >> 4) & 7, k = i & 15;
        float s = 0.f;
        for (int c = 0; c < 16; ++c) s += M1[i1 * 128 + j * 16 + c] * Lg3[c * 256 + k * 16 + d];
        A_T[idx] = s;
    }
    for (int idx = tid; idx < 4096; idx += 256) {
        int e = idx >> 8, mp = idx & 255;
        int m = mp >> 4, p = mp & 15;
        float s = 0.f;
        for (int f = 0; f < 16; ++f) s += Lg5[e * 256 + m * 16 + f] * Lg6[f * 16 + p];
        M2[idx] = s;
    }
}

// ---------------- K0b: Whh2[u][d] = sum_e g4hh[d, n(u), e] * M2hh[e, mp(u)] ----
__global__ __launch_bounds__(256) void k0b_whh(
    const float* __restrict__ g4hh, const float* __restrict__ M2hh,
    float* __restrict__ Whh2)
{
    int n = blockIdx.x;         // 0..15
    int mp = threadIdx.x;       // 0..255
    __shared__ float Ls[256];   // [d][e] slice for this n
    Ls[mp] = g4hh[(mp >> 4) * 256 + n * 16 + (mp & 15)];
    float m2loc[16];
    #pragma unroll
    for (int e = 0; e < 16; ++e) m2loc[e] = M2hh[e * 256 + mp];
    __syncthreads();
    float wv[16];
    #pragma unroll
    for (int d = 0; d < 16; ++d) {
        float s = 0.f;
        #pragma unroll
        for (int e = 0; e < 16; ++e) s = fmaf(Ls[d * 16 + e], m2loc[e], s);
        wv[d] = s;
    }
    float4* dst = (float4*)&Whh2[(size_t)(n * 256 + mp) * 16];
    dst[0] = make_float4(wv[0], wv[1], wv[2], wv[3]);
    dst[1] = make_float4(wv[4], wv[5], wv[6], wv[7]);
    dst[2] = make_float4(wv[8], wv[9], wv[10], wv[11]);
    dst[3] = make_float4(wv[12], wv[13], wv[14], wv[15]);
}

// ---------------- K1: y_ih[row][256] = (x[row]·A_ih)·g4ih ----------------
__global__ __launch_bounds__(256) void k1_zy(
    const float* __restrict__ x, const float* __restrict__ A_T,
    const float* __restrict__ g4, float* __restrict__ y_out)
{
    __shared__ float P[16 * 257];           // partials [d][tid], padded stride
    __shared__ float Q[256];                // [d][s]
    __shared__ __align__(16) float Zf[16];
    int tid = threadIdx.x;

    // thread owns i-quad tid*4..+3; av[j][k] = {A[2k][i], A[2k+1][i]}
    v2f av[4][8];
    #pragma unroll
    for (int j = 0; j < 4; ++j)
        #pragma unroll
        for (int k = 0; k < 8; ++k)
            av[j][k] = mkv2(A_T[(2 * k) * 1024 + tid * 4 + j],
                            A_T[(2 * k + 1) * 1024 + tid * 4 + j]);

    float g4r[16];
    #pragma unroll
    for (int d = 0; d < 16; ++d) g4r[d] = g4[d * 256 + tid];

    int row0 = blockIdx.x * 16;
    float4 xv = *(const float4*)&x[(size_t)row0 * 1024 + tid * 4];
    for (int r = 0; r < 16; ++r) {
        int row = row0 + r;
        v2f pd[8];
        #pragma unroll
        for (int k = 0; k < 8; ++k) {
            v2f acc = xv.x * av[0][k];
            acc += xv.y * av[1][k];
            acc += xv.z * av[2][k];
            acc += xv.w * av[3][k];
            pd[k] = acc;
        }
        #pragma unroll
        for (int k = 0; k < 8; ++k) {
            P[(2 * k) * 257 + tid]     = pd[k].x;
            P[(2 * k + 1) * 257 + tid] = pd[k].y;
        }
        if (r < 15)  // prefetch next row's x (consumed next iter; off barrier path)
            xv = *(const float4*)&x[(size_t)(row + 1) * 1024 + tid * 4];
        bar_lgkm();
        {
            int d = tid & 15, s = tid >> 4;
            float v = 0.f;
            #pragma unroll
            for (int j2 = 0; j2 < 16; ++j2) v += P[d * 257 + s * 16 + j2];
            Q[d * 16 + s] = v;
        }
        bar_lgkm();
        if (tid < 16) {
            float v = 0.f;
            #pragma unroll
            for (int s2 = 0; s2 < 16; ++s2) v += Q[tid * 16 + s2];
            Zf[tid] = v;
        }
        bar_lgkm();
        {
            v2f ya = mkv2(0.f, 0.f);
            const v2f* zf2 = (const v2f*)Zf;
            #pragma unroll
            for (int k = 0; k < 8; ++k) ya += zf2[k] * mkv2(g4r[2 * k], g4r[2 * k + 1]);
            y_out[(size_t)row * 256 + tid] = ya.x + ya.y;
        }
        // no barrier needed: next iter's P writes don't conflict with Zf reads
    }
}

// ---------------- K2: sequential LSTM, one block (CU) per batch row ----------
__global__ __launch_bounds__(1024) void k2_lstm(
    const float* __restrict__ A_T_hh, const float* __restrict__ Whh2,
    const float* __restrict__ M2ih, const float* __restrict__ y_ih_g,
    const float* __restrict__ b_ih, const float* __restrict__ b_hh,
    float* __restrict__ pfdump, float* __restrict__ out)
{
    __shared__ __align__(16) float Lh[1024];
    __shared__ __align__(16) float Pz[32];

    const int tid  = threadIdx.x;
    const int b    = blockIdx.x;
    const int lane = tid & 63;
    const int w    = tid >> 6;
    const int dg   = w >> 1;                 // d-pair group 0..7  -> d = 2dg, 2dg+1
    const int ws   = w & 1;                  // i-half 0..1
    const int mp   = tid & 255;
    const int n0   = tid >> 8;
    const int n0u  = __builtin_amdgcn_readfirstlane(n0);  // wave-uniform (tid>>8 const per wave)

    // z-phase A slice: 2 rows x 8 i, kept in registers (v2f pairs over i)
    const int ibase = ws * 512 + lane * 8;
    v2f a0p[4], a1p[4];
    {
        const v2f* a0v = (const v2f*)&A_T_hh[(2 * dg) * 1024 + ibase];
        const v2f* a1v = (const v2f*)&A_T_hh[(2 * dg + 1) * 1024 + ibase];
        #pragma unroll
        for (int k = 0; k < 4; ++k) { a0p[k] = a0v[k]; a1p[k] = a1v[k]; }
    }

    // folded hh expansion weights: whh[g][k] pairs d=2k,2k+1
    v2f whh[4][8];
    #pragma unroll
    for (int g = 0; g < 4; ++g) {
        const float4* wr4 = (const float4*)&Whh2[(size_t)((n0 + 4 * g) * 256 + mp) * 16];
        float4 f0 = wr4[0], f1 = wr4[1], f2 = wr4[2], f3 = wr4[3];
        whh[g][0] = mkv2(f0.x, f0.y); whh[g][1] = mkv2(f0.z, f0.w);
        whh[g][2] = mkv2(f1.x, f1.y); whh[g][3] = mkv2(f1.z, f1.w);
        whh[g][4] = mkv2(f2.x, f2.y); whh[g][5] = mkv2(f2.z, f2.w);
        whh[g][6] = mkv2(f3.x, f3.y); whh[g][7] = mkv2(f3.z, f3.w);
    }
    float m2i[16];
    #pragma unroll
    for (int e = 0; e < 16; ++e) m2i[e] = M2ih[e * 256 + mp];
    float bias0 = b_ih[tid]        + b_hh[tid];
    float bias1 = b_ih[1024 + tid] + b_hh[1024 + tid];
    float bias2 = b_ih[2048 + tid] + b_hh[2048 + tid];
    float bias3 = b_ih[3072 + tid] + b_hh[3072 + tid];

    Lh[tid] = 0.f;
    float h = 0.f, c = 0.f;
    __syncthreads();

    const float* yrow = y_ih_g + (size_t)b * (NT * 256);
    float*       orow = out + (size_t)b * (NT * 1024);

    for (int t = 0; t < NT; ++t) {
        // --- (A) z partials: wave (dg,ws) covers d={2dg,2dg+1}, i in [ws*512, +512)
        float p0, p1;
        {
            const v2f* hv2 = (const v2f*)&Lh[ibase];
            v2f hp0 = hv2[0], hp1 = hv2[1], hp2 = hv2[2], hp3 = hv2[3];
            v2f s0 = hp0 * a0p[0]; s0 += hp1 * a0p[1]; s0 += hp2 * a0p[2]; s0 += hp3 * a0p[3];
            v2f s1 = hp0 * a1p[0]; s1 += hp1 * a1p[1]; s1 += hp2 * a1p[2]; s1 += hp3 * a1p[3];
            p0 = s0.x + s0.y;
            p1 = s1.x + s1.y;
        }
        #pragma unroll
        for (int m = 1; m <= 32; m <<= 1) {
            p0 += __shfl_xor(p0, m, 64);
            p1 += __shfl_xor(p1, m, 64);
        }
        if (lane == 0) *(v2f*)&Pz[ws * 16 + 2 * dg] = mkv2(p0, p1);
        bar_lgkm();

        // --- (C) gather z = half0 + half1 (broadcast reads)
        v2f zp[8];
        {
            const float4* pz4 = (const float4*)Pz;
            float4 q0 = pz4[0], q1 = pz4[1], q2 = pz4[2], q3 = pz4[3];
            float4 r0 = pz4[4], r1 = pz4[5], r2 = pz4[6], r3 = pz4[7];
            float4 s0 = make_float4(q0.x + r0.x, q0.y + r0.y, q0.z + r0.z, q0.w + r0.w);
            float4 s1 = make_float4(q1.x + r1.x, q1.y + r1.y, q1.z + r1.z, q1.w + r1.w);
            float4 s2 = make_float4(q2.x + r2.x, q2.y + r2.y, q2.z + r2.z, q2.w + r2.w);
            float4 s3 = make_float4(q3.x + r3.x, q3.y + r3.y, q3.z + r3.z, q3.w + r3.w);
            zp[0] = mkv2(s0.x, s0.y); zp[1] = mkv2(s0.z, s0.w);
            zp[2] = mkv2(s1.x, s1.y); zp[3] = mkv2(s1.z, s1.w);
            zp[4] = mkv2(s2.x, s2.y); zp[5] = mkv2(s2.z, s2.w);
            zp[6] = mkv2(s3.x, s3.y); zp[7] = mkv2(s3.z, s3.w);
        }

        // --- (D1) hh contribution: acc[g] = bias + sum_d z[d]*whh[g][d]  (pk fma)
        float acc0, acc1, acc2, acc3;
        {
            v2f a0 = zp[0] * whh[0][0], a1 = zp[0] * whh[1][0];
            v2f a2 = zp[0] * whh[2][0], a3 = zp[0] * whh[3][0];
            #pragma unroll
            for (int k = 1; k < 8; ++k) {
                a0 += zp[k] * whh[0][k];
                a1 += zp[k] * whh[1][k];
                a2 += zp[k] * whh[2][k];
                a3 += zp[k] * whh[3][k];
            }
            acc0 = bias0 + a0.x + a0.y;
            acc1 = bias1 + a1.x + a1.y;
            acc2 = bias2 + a2.x + a2.y;
            acc3 = bias3 + a3.x + a3.y;
        }

        // --- (D2) ih contribution: wave-uniform y addresses (scalar-load friendly)
        {
            const float4* yb4 = (const float4*)(yrow + t * 256);
            #pragma unroll
            for (int g = 0; g < 4; ++g) {
                int base = (n0u + 4 * g) * 4;
                float4 q0 = yb4[base], q1 = yb4[base + 1], q2 = yb4[base + 2], q3 = yb4[base + 3];
                float a = q0.x * m2i[0];
                a = fmaf(q0.y, m2i[1], a);  a = fmaf(q0.z, m2i[2], a);  a = fmaf(q0.w, m2i[3], a);
                a = fmaf(q1.x, m2i[4], a);  a = fmaf(q1.y, m2i[5], a);  a = fmaf(q1.z, m2i[6], a);
                a = fmaf(q1.w, m2i[7], a);  a = fmaf(q2.x, m2i[8], a);  a = fmaf(q2.y, m2i[9], a);
                a = fmaf(q2.z, m2i[10], a); a = fmaf(q2.w, m2i[11], a); a = fmaf(q3.x, m2i[12], a);
                a = fmaf(q3.y, m2i[13], a); a = fmaf(q3.z, m2i[14], a); a = fmaf(q3.w, m2i[15], a);
                if (g == 0) acc0 += a;
                else if (g == 1) acc1 += a;
                else if (g == 2) acc2 += a;
                else acc3 += a;
            }
        }

        // --- (E) LSTM cell
        float ig = sigm(acc0);
        float fg = sigm(acc1);
        float gg = tanh_fast(acc2);
        float og = sigm(acc3);
        c = fg * c + ig * gg;
        h = og * tanh_fast(c);

        Lh[tid] = h;
        orow[t * 1024 + tid] = h;   // fire-and-forget (barrier doesn't drain vmcnt)

        // --- (F) L2 prefetch of y(t+1); dump store is never read
        if (tid < 256) {
            int tn = (t + 1 < NT) ? (t + 1) : (NT - 1);
            pfdump[tid] = yrow[tn * 256 + tid];
        }
        bar_lgkm();
    }

    out[HID_OFF + b * 1024 + tid] = h;
    out[HID_OFF + HC_SZ + b * 1024 + tid] = c;
}

extern "C" void kernel_launch(void* const* d_in, const int* in_sizes, int n_in,
                              void* d_out, int out_size, void* d_ws, size_t ws_size,
                              hipStream_t stream) {
    const float* x     = (const float*)d_in[0];
    const float* ihg1  = (const float*)d_in[1];
    const float* ihg2  = (const float*)d_in[2];
    const float* ihg3  = (const float*)d_in[3];
    const float* ihg4  = (const float*)d_in[4];
    const float* ihg5  = (const float*)d_in[5];
    const float* ihg6  = (const float*)d_in[6];
    const float* hhg1  = (const float*)d_in[7];
    const float* hhg2  = (const float*)d_in[8];
    const float* hhg3  = (const float*)d_in[9];
    const float* hhg4  = (const float*)d_in[10];
    const float* hhg5  = (const float*)d_in[11];
    const float* hhg6  = (const float*)d_in[12];
    const float* b_ih  = (const float*)d_in[13];
    const float* b_hh  = (const float*)d_in[14];
    float* out = (float*)d_out;

    float* ws     = (float*)d_ws;
    float* ATih   = ws;
    float* AThh   = ws + 16384;
    float* M2ih   = ws + 32768;
    float* M2hh   = ws + 36864;
    float* Whh2   = ws + 40960;
    float* pfdump = ws + 106496;
    float* yih    = ws + 106752;

    hipLaunchKernelGGL(k0_build, dim3(2), dim3(256), 0, stream,
                       ihg1, ihg2, ihg3, ihg5, ihg6,
                       hhg1, hhg2, hhg3, hhg5, hhg6,
                       ATih, M2ih, AThh, M2hh);
    hipLaunchKernelGGL(k0b_whh, dim3(16), dim3(256), 0, stream,
                       hhg4, M2hh, Whh2);
    hipLaunchKernelGGL(k1_zy, dim3(2048), dim3(256), 0, stream,
                       x, ATih, ihg4, yih);
    hipLaunchKernelGGL(k2_lstm, dim3(NB), dim3(1024), 0, stream,
                       AThh, Whh2, M2ih, yih, b_ih, b_hh, pfdump, out);
}

// Round 3
// 1564.338 us; speedup vs baseline: 1.1984x; 1.0765x over previous
//
#include <hip/hip_runtime.h>
#include <math.h>

// Problem constants (fixed by reference)
#define NB   64
#define NT   512
#define DH   1024
#define HID_OFF  33554432   // 64*512*1024
#define HC_SZ    65536      // 64*1024

// ws layout (floats):
//  [0]       A_T_ih [16][1024]
//  [16384]   A_T_hh [16][1024]
//  [32768]   M2ih   [16][256]
//  [36864]   M2hh   [16][256]
//  [40960]   Whh2   [4096][16]   (g4hh x M2hh folded, u-major)
//  [106496]  pfdump [1024]       (prefetch sink, never read)
//  [107520]  y_ih   [32768][256] (32 MB)

typedef float v2f __attribute__((ext_vector_type(2)));

__device__ __forceinline__ v2f mkv2(float a, float b) { v2f r; r.x = a; r.y = b; return r; }

__device__ __forceinline__ void bar_lgkm() {
    // barrier that waits only for LDS/SMEM ops (NOT vmcnt) — keeps HBM
    // stores/prefetches out of the per-step critical path.
    asm volatile("s_waitcnt lgkmcnt(0)\n\ts_barrier" ::: "memory");
}

// DPP wave64 sum: result valid in lane 63. VALU-pipe only (no DS traffic).
template<int CTRL>
__device__ __forceinline__ float dpp_add(float v) {
    int m = __builtin_amdgcn_update_dpp(0, __builtin_bit_cast(int, v), CTRL, 0xf, 0xf, true);
    return v + __builtin_bit_cast(float, m);
}
__device__ __forceinline__ float wave_red_sum(float v) {
    v = dpp_add<0x111>(v);   // row_shr:1
    v = dpp_add<0x112>(v);   // row_shr:2
    v = dpp_add<0x114>(v);   // row_shr:4
    v = dpp_add<0x118>(v);   // row_shr:8  -> lane15/31/47/63 have row sums
    v = dpp_add<0x142>(v);   // row_bcast:15 -> lane31 = rows0-1, lane63 = rows2-3
    v = dpp_add<0x143>(v);   // row_bcast:31 -> lane63 = total
    return v;
}

__device__ __forceinline__ float sigm(float x) { return 1.f / (1.f + __expf(-x)); }
__device__ __forceinline__ float tanh_fast(float x) {
    float e = __expf(2.f * x);
    return 1.f - 2.f / (e + 1.f);
}

// ---------------- K0a: build A_T = (g1*g2*g3)^T and M2 = g5*g6 (both param sets)
__global__ __launch_bounds__(256) void k0_build(
    const float* __restrict__ g1a, const float* __restrict__ g2a,
    const float* __restrict__ g3a, const float* __restrict__ g5a,
    const float* __restrict__ g6a,
    const float* __restrict__ g1b, const float* __restrict__ g2b,
    const float* __restrict__ g3b, const float* __restrict__ g5b,
    const float* __restrict__ g6b,
    float* __restrict__ ATa, float* __restrict__ M2a,
    float* __restrict__ ATb, float* __restrict__ M2b)
{
    const float* g1 = blockIdx.x ? g1b : g1a;
    const float* g2 = blockIdx.x ? g2b : g2a;
    const float* g3 = blockIdx.x ? g3b : g3a;
    const float* g5 = blockIdx.x ? g5b : g5a;
    const float* g6 = blockIdx.x ? g6b : g6a;
    float* A_T = blockIdx.x ? ATb : ATa;
    float* M2  = blockIdx.x ? M2b : M2a;

    __shared__ float Lg1[128], Lg2[2048], Lg3[4096], Lg5[4096], Lg6[256], M1[1024];
    int tid = threadIdx.x;
    for (int i = tid; i < 128;  i += 256) Lg1[i] = g1[i];
    for (int i = tid; i < 2048; i += 256) Lg2[i] = g2[i];
    for (int i = tid; i < 4096; i += 256) Lg3[i] = g3[i];
    for (int i = tid; i < 4096; i += 256) Lg5[i] = g5[i];
    for (int i = tid; i < 256;  i += 256) Lg6[i] = g6[i];
    __syncthreads();
    for (int idx = tid; idx < 1024; idx += 256) {
        int i1 = idx >> 7, j = (idx >> 4) & 7, c = idx & 15;
        float s = 0.f;
        for (int a = 0; a < 16; ++a) s += Lg1[i1 * 16 + a] * Lg2[a * 128 + j * 16 + c];
        M1[idx] = s;
    }
    __syncthreads();
    // split A_T across blockIdx.y (4 slices of 4096)
    int base = 4096 * blockIdx.y;
    for (int idx = base + tid; idx < base + 4096; idx += 256) {
        int d = idx >> 10, i = idx & 1023;
        int i1 = i >> 7, j = (i >> 4) & 7, k = i & 15;
        float s = 0.f;
        for (int c = 0; c < 16; ++c) s += M1[i1 * 128 + j * 16 + c] * Lg3[c * 256 + k * 16 + d];
        A_T[idx] = s;
    }
    if (blockIdx.y == 0) {
        for (int idx = tid; idx < 4096; idx += 256) {
            int e = idx >> 8, mp = idx & 255;
            int m = mp >> 4, p = mp & 15;
            float s = 0.f;
            for (int f = 0; f < 16; ++f) s += Lg5[e * 256 + m * 16 + f] * Lg6[f * 16 + p];
            M2[idx] = s;
        }
    }
}

// ---------------- K0b: Whh2[u][d] = sum_e g4hh[d, n(u), e] * M2hh[e, mp(u)] ----
__global__ __launch_bounds__(256) void k0b_whh(
    const float* __restrict__ g4hh, const float* __restrict__ M2hh,
    float* __restrict__ Whh2)
{
    int n = blockIdx.x;         // 0..15
    int mp = threadIdx.x;       // 0..255
    __shared__ float Ls[256];   // [d][e] slice for this n
    Ls[mp] = g4hh[(mp >> 4) * 256 + n * 16 + (mp & 15)];
    float m2loc[16];
    #pragma unroll
    for (int e = 0; e < 16; ++e) m2loc[e] = M2hh[e * 256 + mp];
    __syncthreads();
    float wv[16];
    #pragma unroll
    for (int d = 0; d < 16; ++d) {
        float s = 0.f;
        #pragma unroll
        for (int e = 0; e < 16; ++e) s = fmaf(Ls[d * 16 + e], m2loc[e], s);
        wv[d] = s;
    }
    float4* dst = (float4*)&Whh2[(size_t)(n * 256 + mp) * 16];
    dst[0] = make_float4(wv[0], wv[1], wv[2], wv[3]);
    dst[1] = make_float4(wv[4], wv[5], wv[6], wv[7]);
    dst[2] = make_float4(wv[8], wv[9], wv[10], wv[11]);
    dst[3] = make_float4(wv[12], wv[13], wv[14], wv[15]);
}

// ---------------- K1: y_ih[row][256] = (x[row]·A_ih)·g4ih, 2 waves per row ----
// grid 1024 x 256thr: 4 waves/block = 2 row-slots/block; 16 rows per slot.
__global__ __launch_bounds__(256) void k1_zy(
    const float* __restrict__ x, const float* __restrict__ A_T,
    const float* __restrict__ g4, float* __restrict__ y_out)
{
    __shared__ __align__(16) float Z[2][2][2][16];  // [slot][row-parity][wave-half][16]

    const int tid  = threadIdx.x;
    const int lane = tid & 63;
    const int w    = tid >> 6;          // 0..3
    const int s    = w >> 1;            // slot in block
    const int wp   = w & 1;             // i-half
    const int i0   = wp * 512 + lane * 8;

    // A slice: av[ip][dd] = {A[2dd][i0+ip], A[2dd+1][i0+ip]}  (128 VGPR, reused 16 rows)
    v2f av[8][8];
    #pragma unroll
    for (int d = 0; d < 16; ++d) {
        float Ar[8];
        *(float4*)&Ar[0] = *(const float4*)&A_T[d * 1024 + i0];
        *(float4*)&Ar[4] = *(const float4*)&A_T[d * 1024 + i0 + 4];
        #pragma unroll
        for (int ip = 0; ip < 8; ++ip) {
            if (d & 1) av[ip][d >> 1].y = Ar[ip];
            else       av[ip][d >> 1].x = Ar[ip];
        }
    }
    // g4 slice for this thread's two outputs u0, u1
    const int u0 = wp * 128 + lane;
    const int u1 = u0 + 64;
    float g4r0[16], g4r1[16];
    #pragma unroll
    for (int d = 0; d < 16; ++d) {
        g4r0[d] = g4[d * 256 + u0];
        g4r1[d] = g4[d * 256 + u1];
    }

    const int rbase = (blockIdx.x * 2 + s) * 16;
    float xr[8];
    *(float4*)&xr[0] = *(const float4*)&x[(size_t)rbase * 1024 + i0];
    *(float4*)&xr[4] = *(const float4*)&x[(size_t)rbase * 1024 + i0 + 4];

    for (int rr = 0; rr < 16; ++rr) {
        const int row = rbase + rr;
        const int rp  = rr & 1;
        // prefetch next row's x
        float xn[8];
        if (rr < 15) {
            *(float4*)&xn[0] = *(const float4*)&x[(size_t)(row + 1) * 1024 + i0];
            *(float4*)&xn[4] = *(const float4*)&x[(size_t)(row + 1) * 1024 + i0 + 4];
        }
        // partials over this lane's 8 i-values, all 16 d (v2f pairs)
        v2f p[8];
        #pragma unroll
        for (int dd = 0; dd < 8; ++dd) p[dd] = xr[0] * av[0][dd];
        #pragma unroll
        for (int ip = 1; ip < 8; ++ip)
            #pragma unroll
            for (int dd = 0; dd < 8; ++dd) p[dd] += xr[ip] * av[ip][dd];
        // DPP reduce (VALU-pipe), lane63 holds sums
        #pragma unroll
        for (int dd = 0; dd < 8; ++dd) {
            float sx = wave_red_sum(p[dd].x);
            float sy = wave_red_sum(p[dd].y);
            if (lane == 63) *(v2f*)&Z[s][rp][wp][2 * dd] = mkv2(sx, sy);
        }
        bar_lgkm();
        // gather z = half0 + half1 (broadcast b128 reads)
        float zs[16];
        {
            const float4* za = (const float4*)&Z[s][rp][0][0];
            const float4* zb = (const float4*)&Z[s][rp][1][0];
            float4 a0 = za[0], a1 = za[1], a2 = za[2], a3 = za[3];
            float4 b0 = zb[0], b1 = zb[1], b2 = zb[2], b3 = zb[3];
            *(float4*)&zs[0]  = make_float4(a0.x + b0.x, a0.y + b0.y, a0.z + b0.z, a0.w + b0.w);
            *(float4*)&zs[4]  = make_float4(a1.x + b1.x, a1.y + b1.y, a1.z + b1.z, a1.w + b1.w);
            *(float4*)&zs[8]  = make_float4(a2.x + b2.x, a2.y + b2.y, a2.z + b2.z, a2.w + b2.w);
            *(float4*)&zs[12] = make_float4(a3.x + b3.x, a3.y + b3.y, a3.z + b3.z, a3.w + b3.w);
        }
        float y0 = zs[0] * g4r0[0], y1 = zs[0] * g4r1[0];
        #pragma unroll
        for (int d = 1; d < 16; ++d) {
            y0 = fmaf(zs[d], g4r0[d], y0);
            y1 = fmaf(zs[d], g4r1[d], y1);
        }
        y_out[(size_t)row * 256 + u0] = y0;
        y_out[(size_t)row * 256 + u1] = y1;
        #pragma unroll
        for (int ip = 0; ip < 8; ++ip) xr[ip] = xn[ip];
        // no 2nd barrier: next write goes to row-parity ^1 buffer; the write
        // after that is separated from this read by the next bar_lgkm.
    }
}

// ---------------- K2: sequential LSTM, one block (CU) per batch row ----------
__global__ __launch_bounds__(1024) void k2_lstm(
    const float* __restrict__ A_T_hh, const float* __restrict__ Whh2,
    const float* __restrict__ M2ih, const float* __restrict__ y_ih_g,
    const float* __restrict__ b_ih, const float* __restrict__ b_hh,
    float* __restrict__ pfdump, float* __restrict__ out)
{
    __shared__ __align__(16) float Lh[1024];
    __shared__ __align__(16) float Lz[2][16];   // parity double-buffered z accumulators

    const int tid  = threadIdx.x;
    const int b    = blockIdx.x;
    const int lane = tid & 63;
    const int w    = tid >> 6;
    const int dg   = w >> 1;                 // d-pair group 0..7 -> d = 2dg, 2dg+1
    const int wsl  = w & 1;                  // i-half
    const int mp   = tid & 255;
    const int n0   = tid >> 8;               // 0..3, wave-uniform

    // z-phase A slice: 2 d-rows x 8 i per lane, stride-2 v2f (2-way LDS aliasing = free)
    const int ibase = wsl * 512 + 2 * lane;
    v2f a0p[4], a1p[4];
    #pragma unroll
    for (int k = 0; k < 4; ++k) {
        a0p[k] = *(const v2f*)&A_T_hh[(2 * dg) * 1024 + ibase + 128 * k];
        a1p[k] = *(const v2f*)&A_T_hh[(2 * dg + 1) * 1024 + ibase + 128 * k];
    }

    // folded hh expansion weights: whh[g][k] pairs d=2k,2k+1
    v2f whh[4][8];
    #pragma unroll
    for (int g = 0; g < 4; ++g) {
        const float4* wr4 = (const float4*)&Whh2[(size_t)((n0 + 4 * g) * 256 + mp) * 16];
        float4 f0 = wr4[0], f1 = wr4[1], f2 = wr4[2], f3 = wr4[3];
        whh[g][0] = mkv2(f0.x, f0.y); whh[g][1] = mkv2(f0.z, f0.w);
        whh[g][2] = mkv2(f1.x, f1.y); whh[g][3] = mkv2(f1.z, f1.w);
        whh[g][4] = mkv2(f2.x, f2.y); whh[g][5] = mkv2(f2.z, f2.w);
        whh[g][6] = mkv2(f3.x, f3.y); whh[g][7] = mkv2(f3.z, f3.w);
    }
    float m2i[16];
    #pragma unroll
    for (int e = 0; e < 16; ++e) m2i[e] = M2ih[e * 256 + mp];
    float bias0 = b_ih[tid]        + b_hh[tid];
    float bias1 = b_ih[1024 + tid] + b_hh[1024 + tid];
    float bias2 = b_ih[2048 + tid] + b_hh[2048 + tid];
    float bias3 = b_ih[3072 + tid] + b_hh[3072 + tid];

    Lh[tid] = 0.f;
    if (tid < 32) ((float*)Lz)[tid] = 0.f;
    float h = 0.f, c = 0.f;
    __syncthreads();

    const float* yrow = y_ih_g + (size_t)b * (NT * 256);
    float*       orow = out + (size_t)b * (NT * 1024);
    float pfacc = 0.f;

    for (int t = 0; t < NT; ++t) {
        const int p = t & 1;

        // (0) scalar y loads for THIS step (wave-uniform address -> s_load; lands
        //     during phase A) + L2-warming vector load 4 steps ahead (vmcnt-only).
        const int ybase = __builtin_amdgcn_readfirstlane(t * 256 + n0 * 16);
        float yv[4][16];
        #pragma unroll
        for (int g = 0; g < 4; ++g)
            #pragma unroll
            for (int e = 0; e < 16; ++e)
                yv[g][e] = yrow[ybase + g * 64 + e];
        float ypf = 0.f;
        {
            int tpf = (t + 4 < NT) ? (t + 4) : (NT - 1);
            if (tid < 256) ypf = yrow[tpf * 256 + tid];
        }

        // --- (A) z partials: wave (dg,wsl) covers d={2dg,2dg+1}, i in [wsl*512,+512)
        float p0, p1;
        {
            const v2f* hv2 = (const v2f*)&Lh[ibase];
            v2f hp0 = hv2[0], hp1 = hv2[64], hp2 = hv2[128], hp3 = hv2[192];
            v2f s0 = hp0 * a0p[0]; s0 += hp1 * a0p[1]; s0 += hp2 * a0p[2]; s0 += hp3 * a0p[3];
            v2f s1 = hp0 * a1p[0]; s1 += hp1 * a1p[1]; s1 += hp2 * a1p[2]; s1 += hp3 * a1p[3];
            p0 = s0.x + s0.y;
            p1 = s1.x + s1.y;
        }
        p0 = wave_red_sum(p0);              // DPP, VALU pipe
        p1 = wave_red_sum(p1);
        if (lane == 63) {
            atomicAdd(&Lz[p][2 * dg], p0);      // ds_add_f32: both i-halves combine here
            atomicAdd(&Lz[p][2 * dg + 1], p1);
        }
        bar_lgkm();

        // --- (B) gather z (broadcast b128), compute gates ---
        float zs[16];
        {
            const float4* z4 = (const float4*)&Lz[p][0];
            *(float4*)&zs[0]  = z4[0];
            *(float4*)&zs[4]  = z4[1];
            *(float4*)&zs[8]  = z4[2];
            *(float4*)&zs[12] = z4[3];
        }
        // D1: hh contribution (pk fma over d-pairs)
        float acc0, acc1, acc2, acc3;
        {
            const v2f* zp = (const v2f*)zs;
            v2f A0 = zp[0] * whh[0][0], A1 = zp[0] * whh[1][0];
            v2f A2 = zp[0] * whh[2][0], A3 = zp[0] * whh[3][0];
            #pragma unroll
            for (int k = 1; k < 8; ++k) {
                A0 += zp[k] * whh[0][k];
                A1 += zp[k] * whh[1][k];
                A2 += zp[k] * whh[2][k];
                A3 += zp[k] * whh[3][k];
            }
            acc0 = bias0 + A0.x + A0.y;
            acc1 = bias1 + A1.x + A1.y;
            acc2 = bias2 + A2.x + A2.y;
            acc3 = bias3 + A3.x + A3.y;
        }
        // D2: ih contribution (sgpr y * vgpr m2i)
        #pragma unroll
        for (int e = 0; e < 16; ++e) {
            acc0 = fmaf(yv[0][e], m2i[e], acc0);
            acc1 = fmaf(yv[1][e], m2i[e], acc1);
            acc2 = fmaf(yv[2][e], m2i[e], acc2);
            acc3 = fmaf(yv[3][e], m2i[e], acc3);
        }

        // --- (E) LSTM cell
        float ig = sigm(acc0);
        float fg = sigm(acc1);
        float gg = tanh_fast(acc2);
        float og = sigm(acc3);
        c = fg * c + ig * gg;
        h = og * tanh_fast(c);

        Lh[tid] = h;
        orow[t * 1024 + tid] = h;           // fire-and-forget (vmcnt, not drained by bar)
        if (tid < 16) Lz[p ^ 1][tid] = 0.f; // re-zero other parity for step t+2
        pfacc += ypf;                        // forces the L2-warm load to retire
        bar_lgkm();
    }

    out[HID_OFF + b * 1024 + tid] = h;
    out[HID_OFF + HC_SZ + b * 1024 + tid] = c;
    if (tid < 256) pfdump[tid] = pfacc;      // sink (ws, never read)
}

extern "C" void kernel_launch(void* const* d_in, const int* in_sizes, int n_in,
                              void* d_out, int out_size, void* d_ws, size_t ws_size,
                              hipStream_t stream) {
    const float* x     = (const float*)d_in[0];
    const float* ihg1  = (const float*)d_in[1];
    const float* ihg2  = (const float*)d_in[2];
    const float* ihg3  = (const float*)d_in[3];
    const float* ihg4  = (const float*)d_in[4];
    const float* ihg5  = (const float*)d_in[5];
    const float* ihg6  = (const float*)d_in[6];
    const float* hhg1  = (const float*)d_in[7];
    const float* hhg2  = (const float*)d_in[8];
    const float* hhg3  = (const float*)d_in[9];
    const float* hhg4  = (const float*)d_in[10];
    const float* hhg5  = (const float*)d_in[11];
    const float* hhg6  = (const float*)d_in[12];
    const float* b_ih  = (const float*)d_in[13];
    const float* b_hh  = (const float*)d_in[14];
    float* out = (float*)d_out;

    float* ws     = (float*)d_ws;
    float* ATih   = ws;
    float* AThh   = ws + 16384;
    float* M2ih   = ws + 32768;
    float* M2hh   = ws + 36864;
    float* Whh2   = ws + 40960;
    float* pfdump = ws + 106496;
    float* yih    = ws + 107520;

    hipLaunchKernelGGL(k0_build, dim3(2, 4), dim3(256), 0, stream,
                       ihg1, ihg2, ihg3, ihg5, ihg6,
                       hhg1, hhg2, hhg3, hhg5, hhg6,
                       ATih, M2ih, AThh, M2hh);
    hipLaunchKernelGGL(k0b_whh, dim3(16), dim3(256), 0, stream,
                       hhg4, M2hh, Whh2);
    hipLaunchKernelGGL(k1_zy, dim3(1024), dim3(256), 0, stream,
                       x, ATih, ihg4, yih);
    hipLaunchKernelGGL(k2_lstm, dim3(NB), dim3(1024), 0, stream,
                       AThh, Whh2, M2ih, yih, b_ih, b_hh, pfdump, out);
}